// Round 5
// baseline (241.509 us; speedup 1.0000x reference)
//
#include <hip/hip_runtime.h>
#include <math.h>

#define TOKENS 16384
#define HIDDEN 2048
#define NEXP   64
#define MT     16                  // tokens per block (R5: halved -> 2x blocks)
#define NBLK   (TOKENS / MT)       // 1024

#define GATES_OFF (TOKENS * 2)
#define SEL_OFF   (GATES_OFF + TOKENS * NEXP)
#define Z_OFF     (SEL_OFF + TOKENS * 2)

#define WIMG_BYTES (NEXP * HIDDEN * 2 * 2)   // 512 KB: fp16 wh+wl fragment image

typedef __attribute__((ext_vector_type(8))) _Float16 f16x8;
typedef __attribute__((ext_vector_type(4))) float    f32x4;

// Self-resetting cross-block z-loss accumulator (verified pattern from R4:
// module globals start 0; last-arriving block reads+resets; stream-serialized
// across graph replays).
__device__ float    g_zacc = 0.f;
__device__ unsigned g_cnt  = 0u;

__device__ __forceinline__ float wave_sum64(float v) {
    #pragma unroll
    for (int s = 1; s < 64; s <<= 1) v += __shfl_xor(v, s, 64);
    return v;
}

// ---------------------------------------------------------------------------
// Setup: convert w [64,2048] fp32 -> fp16 (hi, lo*4096) fragment image in ws.
// Image: [chunk 32][r 1024] of 16-B slots; r = eh*512 + term*256 + kh*128 +
// nt*64 + lane. Slot lane l: n = l&15, klocal = (l>>4)*8 + j (verified
// 16x16x32 B-operand layout). [harness-verified R3]
// ---------------------------------------------------------------------------
__global__ __launch_bounds__(256) void wconvert(
    const float* __restrict__ w, uint4* __restrict__ wimg)
{
    const int s = blockIdx.x * 256 + threadIdx.x;     // 0..32767
    const int c    = s >> 10;
    const int r    = s & 1023;
    const int l    = r & 63;
    const int nt   = (r >> 6) & 1;
    const int kh   = (r >> 7) & 1;
    const int term = (r >> 8) & 1;
    const int eh   = (r >> 9) & 1;
    const int e = eh * 32 + nt * 16 + (l & 15);
    const int k = c * 64 + kh * 32 + (l >> 4) * 8;

    const float* src = w + (size_t)e * HIDDEN + k;
    union { _Float16 f[8]; uint4 u; } o;
    #pragma unroll
    for (int j = 0; j < 8; ++j) {
        const float v = src[j];
        const _Float16 h = (_Float16)v;
        o.f[j] = (term == 0) ? h : (_Float16)((v - (float)h) * 4096.f);
    }
    wimg[s] = o.u;
}

// ---------------------------------------------------------------------------
// fp32 -> (hi, lo*4096) fp16x8 split of 8 floats (two float4)
// ---------------------------------------------------------------------------
__device__ __forceinline__ void cvt_split(const float4 a, const float4 b,
                                          f16x8& hi, f16x8& lo) {
    union { _Float16 f[8]; f16x8 v; } H, L;
    #pragma unroll
    for (int j = 0; j < 4; ++j) {
        const float s0 = (&a.x)[j];
        const float s1 = (&b.x)[j];
        const _Float16 h0 = (_Float16)s0;
        const _Float16 h1 = (_Float16)s1;
        H.f[j]     = h0;
        H.f[j + 4] = h1;
        L.f[j]     = (_Float16)((s0 - (float)h0) * 4096.f);
        L.f[j + 4] = (_Float16)((s1 - (float)h1) * 4096.f);
    }
    hi = H.v; lo = L.v;
}

// ---------------------------------------------------------------------------
// One 32-k pipeline stage: raw fp32 A (1 token-tile: 16 rows x 8 floats via
// 2 float4/lane) + fp16 B frags from wimg. Compile-time indices -> VGPRs.
// ---------------------------------------------------------------------------
struct Stage {
    float4 a0, a1;         // raw x: lane row (l&15), k += (l>>4)*8
    f16x8  bh[4], bl[4];   // B frags g: e = (g>>1)*32 + (g&1)*16 + (l&15)
};

__device__ __forceinline__ void load_stage(Stage& S, const float* ax0,
                                           const uint4* wB, int s) {
    S.a0 = *(const float4*)(ax0 + s * 32);
    S.a1 = *(const float4*)(ax0 + s * 32 + 4);
    const uint4* p = wB + (s >> 1) * 1024 + (s & 1) * 128;
    S.bh[0] = *(const f16x8*)(p);          // eh0 nt0 hi
    S.bh[1] = *(const f16x8*)(p + 64);     // eh0 nt1 hi
    S.bh[2] = *(const f16x8*)(p + 512);    // eh1 nt0 hi
    S.bh[3] = *(const f16x8*)(p + 576);    // eh1 nt1 hi
    S.bl[0] = *(const f16x8*)(p + 256);
    S.bl[1] = *(const f16x8*)(p + 320);
    S.bl[2] = *(const f16x8*)(p + 768);
    S.bl[3] = *(const f16x8*)(p + 832);
}

__device__ __forceinline__ void consume_stage(
    const Stage& S, f32x4 (&acc0)[4], f32x4 (&acc1)[4])
{
    f16x8 Ah, Al;
    cvt_split(S.a0, S.a1, Ah, Al);
    #pragma unroll
    for (int g = 0; g < 4; ++g) {
        acc0[g] = __builtin_amdgcn_mfma_f32_16x16x32_f16(Ah, S.bh[g], acc0[g], 0, 0, 0);
        acc1[g] = __builtin_amdgcn_mfma_f32_16x16x32_f16(Ah, S.bl[g], acc1[g], 0, 0, 0);
        acc1[g] = __builtin_amdgcn_mfma_f32_16x16x32_f16(Al, S.bh[g], acc1[g], 0, 0, 0);
    }
}

// ---------------------------------------------------------------------------
// R5: parallelism fix. 1024 blocks x 4 waves (MT=16 tokens/block); wave wv
// owns 16 tokens x 64 experts x k in [wv*512, wv*512+512), 16 steps of 32k.
// R4 post-mortem: kernel is LATENCY-bound at 2 blocks/CU (grid-limited
// occupancy 20.8%, all pipes <17%); halving MT doubles blocks -> ~4/CU.
// B restored to fp16 wimg (R4's in-register w-convert added 2x inner VALU
// and 2x B bytes: 100.5 vs ~75 us). Barrier-free loop, depth-2 register
// double-buffer [R3-verified]. LDS only for 4-way k-partial sum + routing.
// z-loss via device atomics (no 3rd kernel).
// ---------------------------------------------------------------------------
__global__ __launch_bounds__(256, 3) void router_main(
    const float* __restrict__ x, const uint4* __restrict__ wimg,
    float* __restrict__ out)
{
    __shared__ __align__(16) float lg[4][MT * 66];   // 16,896 B k-partial logits
    __shared__ float zred[4];

    const int tid  = threadIdx.x;
    const int wv   = __builtin_amdgcn_readfirstlane(tid >> 6);
    const int lane = tid & 63;
    const int t0   = blockIdx.x * MT;

    // A source: lane l reads row t0 + (l&15), k = wv*512 + s*32 + (l>>4)*8
    const float* ax0 = x + (size_t)(t0 + (lane & 15)) * HIDDEN
                         + wv * 512 + (lane >> 4) * 8;

    // B source: wave's k range covers wimg chunks [wv*8, wv*8+8)
    const uint4* wB = wimg + wv * 8192 + lane;

    f32x4 acc0[4], acc1[4];
    #pragma unroll
    for (int g = 0; g < 4; ++g) { acc0[g] = (f32x4)0.f; acc1[g] = (f32x4)0.f; }

    Stage SA, SB;
    load_stage(SA, ax0, wB, 0);
    load_stage(SB, ax0, wB, 1);

    #pragma unroll
    for (int s = 0; s < 16; s += 2) {
        consume_stage(SA, acc0, acc1);
        if (s + 2 < 16) load_stage(SA, ax0, wB, s + 2);
        consume_stage(SB, acc0, acc1);
        if (s + 3 < 16) load_stage(SB, ax0, wB, s + 3);
    }

    // ---- epilogue: write this wave's k-partial logits (hi + lo/4096) ----
    #pragma unroll
    for (int g = 0; g < 4; ++g)
        #pragma unroll
        for (int r = 0; r < 4; ++r) {
            const int tok = (lane >> 4) * 4 + r;                    // C/D row
            const int e   = (g >> 1) * 32 + (g & 1) * 16 + (lane & 15);
            lg[wv][tok * 66 + e] = acc0[g][r] + acc1[g][r] * (1.f / 4096.f);
        }
    __syncthreads();

    // ---- routing (R1-verified math): wave handles 4 tokens, lane = expert ----
    float zsum = 0.f;
    for (int tt = 0; tt < 4; ++tt) {
        const int t = wv * 4 + tt;
        const int li = t * 66 + lane;
        const float v = lg[0][li] + lg[1][li] + lg[2][li] + lg[3][li];

        float bv = v; int bi = lane;
        #pragma unroll
        for (int s = 1; s < 64; s <<= 1) {
            const float ov = __shfl_xor(bv, s, 64);
            const int   oi = __shfl_xor(bi, s, 64);
            if (ov > bv || (ov == bv && oi < bi)) { bv = ov; bi = oi; }
        }
        const float max1 = bv; const int s1 = bi;

        const float e1 = expf(v - max1);
        const float sume = wave_sum64(e1);
        out[GATES_OFF + (size_t)(t0 + t) * NEXP + lane] = e1 / sume;
        const float lse = max1 + logf(sume);
        zsum += lse * lse;

        const bool mask1 = (max1 - v) > 0.02f * fmaxf(fabsf(v), max1);
        const float sum1 = wave_sum64(mask1 ? 0.f : e1);

        float bv2 = (lane == s1) ? -INFINITY : v; int bi2 = lane;
        #pragma unroll
        for (int s = 1; s < 64; s <<= 1) {
            const float ov = __shfl_xor(bv2, s, 64);
            const int   oi = __shfl_xor(bi2, s, 64);
            if (ov > bv2 || (ov == bv2 && oi < bi2)) { bv2 = ov; bi2 = oi; }
        }
        const float max2 = bv2; const int s2 = bi2;

        const bool mask2 = (max2 - v) > 0.02f * fmaxf(fabsf(v), max2);
        const float p2v = (mask2 || lane == s1) ? 0.f : expf(v - max2);
        const float sum2 = wave_sum64(p2v);

        if (lane == 0) {
            const size_t trow = (size_t)(t0 + t) * 2;
            out[trow + 0] = 1.f / sum1;
            out[trow + 1] = 1.f / sum2;
            out[SEL_OFF + trow + 0] = (float)s1;
            out[SEL_OFF + trow + 1] = (float)s2;
        }
    }

    if (lane == 0) zred[wv] = zsum;
    __syncthreads();

    // ---- z-loss finalize via device-scope atomics [R4-verified pattern] ----
    if (tid == 0) {
        const float bz = zred[0] + zred[1] + zred[2] + zred[3];
        atomicAdd(&g_zacc, bz);
        __threadfence();
        const unsigned old = atomicAdd(&g_cnt, 1u);
        if (old == NBLK - 1) {
            __threadfence();
            const float tot = atomicExch(&g_zacc, 0.f);
            atomicExch(&g_cnt, 0u);
            out[Z_OFF] = 0.001f * (tot / (float)TOKENS);
        }
    }
}

extern "C" void kernel_launch(void* const* d_in, const int* in_sizes, int n_in,
                              void* d_out, int out_size, void* d_ws, size_t ws_size,
                              hipStream_t stream) {
    const float* x = (const float*)d_in[0];   // [16384, 2048] fp32
    const float* w = (const float*)d_in[1];   // [64, 2048] fp32
    float* out = (float*)d_out;               // mult(32768) | gates(1048576) | sel(32768) | z(1)

    uint4* wimg = (uint4*)d_ws;               // 512 KB

    wconvert<<<128, 256, 0, stream>>>(w, wimg);
    router_main<<<NBLK, 256, 0, stream>>>(x, wimg, out);
}

// Round 6
// 218.798 us; speedup vs baseline: 1.1038x; 1.1038x over previous
//
#include <hip/hip_runtime.h>
#include <math.h>

#define TOKENS 16384
#define HIDDEN 2048
#define NEXP   64
#define MT     16                  // tokens per block
#define NBLK   (TOKENS / MT)       // 1024

#define GATES_OFF (TOKENS * 2)
#define SEL_OFF   (GATES_OFF + TOKENS * NEXP)
#define Z_OFF     (SEL_OFF + TOKENS * 2)

#define WIMG_BYTES (NEXP * HIDDEN * 2 * 2)   // 512 KB: fp16 wh+wl fragment image

typedef __attribute__((ext_vector_type(8))) _Float16 f16x8;
typedef __attribute__((ext_vector_type(4))) float    f32x4;

__device__ __forceinline__ float wave_sum64(float v) {
    #pragma unroll
    for (int s = 1; s < 64; s <<= 1) v += __shfl_xor(v, s, 64);
    return v;
}

// ---------------------------------------------------------------------------
// Setup: convert w [64,2048] fp32 -> fp16 (hi, lo*4096) fragment image in ws.
// Image: [chunk 32][r 1024] of 16-B slots; r = eh*512 + term*256 + kh*128 +
// nt*64 + lane. Slot lane l: n = l&15, klocal = (l>>4)*8 + j (verified
// 16x16x32 B-operand layout). [harness-verified R3]
// ---------------------------------------------------------------------------
__global__ __launch_bounds__(256) void wconvert(
    const float* __restrict__ w, uint4* __restrict__ wimg)
{
    const int s = blockIdx.x * 256 + threadIdx.x;     // 0..32767
    const int c    = s >> 10;
    const int r    = s & 1023;
    const int l    = r & 63;
    const int nt   = (r >> 6) & 1;
    const int kh   = (r >> 7) & 1;
    const int term = (r >> 8) & 1;
    const int eh   = (r >> 9) & 1;
    const int e = eh * 32 + nt * 16 + (l & 15);
    const int k = c * 64 + kh * 32 + (l >> 4) * 8;

    const float* src = w + (size_t)e * HIDDEN + k;
    union { _Float16 f[8]; uint4 u; } o;
    #pragma unroll
    for (int j = 0; j < 8; ++j) {
        const float v = src[j];
        const _Float16 h = (_Float16)v;
        o.f[j] = (term == 0) ? h : (_Float16)((v - (float)h) * 4096.f);
    }
    wimg[s] = o.u;
}

// ---------------------------------------------------------------------------
// fp32 -> (hi, lo*4096) fp16x8 split of 8 floats (two float4)
// ---------------------------------------------------------------------------
__device__ __forceinline__ void cvt_split(const float4 a, const float4 b,
                                          f16x8& hi, f16x8& lo) {
    union { _Float16 f[8]; f16x8 v; } H, L;
    #pragma unroll
    for (int j = 0; j < 4; ++j) {
        const float s0 = (&a.x)[j];
        const float s1 = (&b.x)[j];
        const _Float16 h0 = (_Float16)s0;
        const _Float16 h1 = (_Float16)s1;
        H.f[j]     = h0;
        H.f[j + 4] = h1;
        L.f[j]     = (_Float16)((s0 - (float)h0) * 4096.f);
        L.f[j + 4] = (_Float16)((s1 - (float)h1) * 4096.f);
    }
    hi = H.v; lo = L.v;
}

// ---------------------------------------------------------------------------
// One 32-k pipeline stage: raw fp32 A (lane row l&15, k += (l>>4)*8) +
// fp16 B frags from wimg. Compile-time indices -> VGPRs (~40 VGPR/stage).
// ---------------------------------------------------------------------------
struct Stage {
    float4 a0, a1;
    f16x8  bh[4], bl[4];
};

__device__ __forceinline__ void load_stage(Stage& S, const float* ax0,
                                           const uint4* wB, int s) {
    S.a0 = *(const float4*)(ax0 + s * 32);
    S.a1 = *(const float4*)(ax0 + s * 32 + 4);
    const uint4* p = wB + (s >> 1) * 1024 + (s & 1) * 128;
    S.bh[0] = *(const f16x8*)(p);          // eh0 nt0 hi
    S.bh[1] = *(const f16x8*)(p + 64);     // eh0 nt1 hi
    S.bh[2] = *(const f16x8*)(p + 512);    // eh1 nt0 hi
    S.bh[3] = *(const f16x8*)(p + 576);    // eh1 nt1 hi
    S.bl[0] = *(const f16x8*)(p + 256);
    S.bl[1] = *(const f16x8*)(p + 320);
    S.bl[2] = *(const f16x8*)(p + 768);
    S.bl[3] = *(const f16x8*)(p + 832);
}

__device__ __forceinline__ void consume_stage(
    const Stage& S, f32x4 (&acc0)[4], f32x4 (&acc1)[4])
{
    f16x8 Ah, Al;
    cvt_split(S.a0, S.a1, Ah, Al);
    #pragma unroll
    for (int g = 0; g < 4; ++g) {
        acc0[g] = __builtin_amdgcn_mfma_f32_16x16x32_f16(Ah, S.bh[g], acc0[g], 0, 0, 0);
        acc1[g] = __builtin_amdgcn_mfma_f32_16x16x32_f16(Ah, S.bl[g], acc1[g], 0, 0, 0);
        acc1[g] = __builtin_amdgcn_mfma_f32_16x16x32_f16(Al, S.bh[g], acc1[g], 0, 0, 0);
    }
}

// ---------------------------------------------------------------------------
// R6: pipeline PINNING. R5 post-mortem: VGPR_Count=44 proved the compiler
// sank all stage loads to their uses (one stage alone needs ~40 VGPRs),
// collapsing the double-buffer -> exposed memory latency every step (100us,
// all pipes <10%). Fix: __builtin_amdgcn_sched_barrier(0) after each
// half-step {consume; refill} forbids load sinking across iterations ->
// results held in regs, counted vmcnt(N) waits, true depth-2 pipeline.
// Also: atomic z-finalize (R4/R5) reverted to zpartial+zfinal -- 2x1024
// same-address device atomics + threadfence serialize at one cacheline.
// Grid/layout identical to R5 (1024 blocks x 4 waves, MT=16, 4-way k-split,
// fp16 wimg B, LDS only for k-partial sum + routing epilogue).
// ---------------------------------------------------------------------------
__global__ __launch_bounds__(256, 3) void router_main(
    const float* __restrict__ x, const uint4* __restrict__ wimg,
    float* __restrict__ out, float* __restrict__ zpartial)
{
    __shared__ __align__(16) float lg[4][MT * 66];   // 16,896 B k-partial logits
    __shared__ float zred[4];

    const int tid  = threadIdx.x;
    const int wv   = __builtin_amdgcn_readfirstlane(tid >> 6);
    const int lane = tid & 63;
    const int t0   = blockIdx.x * MT;

    // A source: lane l reads row t0 + (l&15), k = wv*512 + s*32 + (l>>4)*8
    const float* ax0 = x + (size_t)(t0 + (lane & 15)) * HIDDEN
                         + wv * 512 + (lane >> 4) * 8;

    // B source: wave's k range covers wimg chunks [wv*8, wv*8+8)
    const uint4* wB = wimg + wv * 8192 + lane;

    f32x4 acc0[4], acc1[4];
    #pragma unroll
    for (int g = 0; g < 4; ++g) { acc0[g] = (f32x4)0.f; acc1[g] = (f32x4)0.f; }

    Stage SA, SB;
    load_stage(SA, ax0, wB, 0);
    load_stage(SB, ax0, wB, 1);
    __builtin_amdgcn_sched_barrier(0);   // pin prologue loads before the loop

    #pragma unroll
    for (int s = 0; s < 16; s += 2) {
        // half-step s: consume SA (loaded 1 iter ago), refill for s+2
        consume_stage(SA, acc0, acc1);
        if (s + 2 < 16) load_stage(SA, ax0, wB, s + 2);
        __builtin_amdgcn_sched_barrier(0);   // loads may not sink past here

        // half-step s+1: consume SB, refill for s+3
        consume_stage(SB, acc0, acc1);
        if (s + 3 < 16) load_stage(SB, ax0, wB, s + 3);
        __builtin_amdgcn_sched_barrier(0);
    }

    // ---- epilogue: write this wave's k-partial logits (hi + lo/4096) ----
    #pragma unroll
    for (int g = 0; g < 4; ++g)
        #pragma unroll
        for (int r = 0; r < 4; ++r) {
            const int tok = (lane >> 4) * 4 + r;                    // C/D row
            const int e   = (g >> 1) * 32 + (g & 1) * 16 + (lane & 15);
            lg[wv][tok * 66 + e] = acc0[g][r] + acc1[g][r] * (1.f / 4096.f);
        }
    __syncthreads();

    // ---- routing (R1-verified math): wave handles 4 tokens, lane = expert ----
    float zsum = 0.f;
    for (int tt = 0; tt < 4; ++tt) {
        const int t = wv * 4 + tt;
        const int li = t * 66 + lane;
        const float v = lg[0][li] + lg[1][li] + lg[2][li] + lg[3][li];

        float bv = v; int bi = lane;
        #pragma unroll
        for (int s = 1; s < 64; s <<= 1) {
            const float ov = __shfl_xor(bv, s, 64);
            const int   oi = __shfl_xor(bi, s, 64);
            if (ov > bv || (ov == bv && oi < bi)) { bv = ov; bi = oi; }
        }
        const float max1 = bv; const int s1 = bi;

        const float e1 = expf(v - max1);
        const float sume = wave_sum64(e1);
        out[GATES_OFF + (size_t)(t0 + t) * NEXP + lane] = e1 / sume;
        const float lse = max1 + logf(sume);
        zsum += lse * lse;

        const bool mask1 = (max1 - v) > 0.02f * fmaxf(fabsf(v), max1);
        const float sum1 = wave_sum64(mask1 ? 0.f : e1);

        float bv2 = (lane == s1) ? -INFINITY : v; int bi2 = lane;
        #pragma unroll
        for (int s = 1; s < 64; s <<= 1) {
            const float ov = __shfl_xor(bv2, s, 64);
            const int   oi = __shfl_xor(bi2, s, 64);
            if (ov > bv2 || (ov == bv2 && oi < bi2)) { bv2 = ov; bi2 = oi; }
        }
        const float max2 = bv2; const int s2 = bi2;

        const bool mask2 = (max2 - v) > 0.02f * fmaxf(fabsf(v), max2);
        const float p2v = (mask2 || lane == s1) ? 0.f : expf(v - max2);
        const float sum2 = wave_sum64(p2v);

        if (lane == 0) {
            const size_t trow = (size_t)(t0 + t) * 2;
            out[trow + 0] = 1.f / sum1;
            out[trow + 1] = 1.f / sum2;
            out[SEL_OFF + trow + 0] = (float)s1;
            out[SEL_OFF + trow + 1] = (float)s2;
        }
    }

    if (lane == 0) zred[wv] = zsum;
    __syncthreads();
    if (tid == 0)
        zpartial[blockIdx.x] = zred[0] + zred[1] + zred[2] + zred[3];
}

__global__ __launch_bounds__(256) void zfinal(
    const float* __restrict__ zpartial, float* __restrict__ out)
{
    const int tid = threadIdx.x;                 // 1024 partials, 256 threads
    float v = zpartial[tid] + zpartial[tid + 256]
            + zpartial[tid + 512] + zpartial[tid + 768];
    v = wave_sum64(v);
    __shared__ float red[4];
    if ((tid & 63) == 0) red[tid >> 6] = v;
    __syncthreads();
    if (tid == 0) {
        const float tot = red[0] + red[1] + red[2] + red[3];
        out[Z_OFF] = 0.001f * (tot / (float)TOKENS);
    }
}

extern "C" void kernel_launch(void* const* d_in, const int* in_sizes, int n_in,
                              void* d_out, int out_size, void* d_ws, size_t ws_size,
                              hipStream_t stream) {
    const float* x = (const float*)d_in[0];   // [16384, 2048] fp32
    const float* w = (const float*)d_in[1];   // [64, 2048] fp32
    float* out = (float*)d_out;               // mult(32768) | gates(1048576) | sel(32768) | z(1)

    uint4* wimg     = (uint4*)d_ws;                               // 512 KB
    float* zpartial = (float*)((char*)d_ws + WIMG_BYTES);         // 1024 floats

    wconvert<<<128, 256, 0, stream>>>(w, wimg);
    router_main<<<NBLK, 256, 0, stream>>>(x, wimg, out, zpartial);
    zfinal<<<1, 256, 0, stream>>>(zpartial, out);
}

// Round 7
// 213.554 us; speedup vs baseline: 1.1309x; 1.0246x over previous
//
#include <hip/hip_runtime.h>
#include <math.h>

#define TOKENS 16384
#define HIDDEN 2048
#define NEXP   64
#define MT     16                  // tokens per block
#define NBLK   (TOKENS / MT)       // 1024
#define BK     256                 // k floats per chunk
#define NCH    (HIDDEN / BK)       // 8
#define ROWB   1024                // bytes per row in xbuf (BK*4)

#define GATES_OFF (TOKENS * 2)
#define SEL_OFF   (GATES_OFF + TOKENS * NEXP)
#define Z_OFF     (SEL_OFF + TOKENS * 2)

#define WIMG_BYTES (NEXP * HIDDEN * 2 * 2)   // 512 KB fp16 wh+wl fragment image

typedef __attribute__((ext_vector_type(8))) _Float16 f16x8;
typedef __attribute__((ext_vector_type(4))) float    f32x4;

__device__ __forceinline__ float wave_sum64(float v) {
    #pragma unroll
    for (int s = 1; s < 64; s <<= 1) v += __shfl_xor(v, s, 64);
    return v;
}

// direct global->LDS DMA, 16 B per lane (dest = uniform base + lane*16)
__device__ __forceinline__ void dma16(const void* g, void* l) {
    __builtin_amdgcn_global_load_lds(
        (const __attribute__((address_space(1))) unsigned int*)g,
        (__attribute__((address_space(3))) unsigned int*)l, 16, 0, 0);
}

// ---------------------------------------------------------------------------
// Setup: w [64,2048] fp32 -> fp16 (hi, lo*4096) fragment image. [verified R3]
// ---------------------------------------------------------------------------
__global__ __launch_bounds__(256) void wconvert(
    const float* __restrict__ w, uint4* __restrict__ wimg)
{
    const int s = blockIdx.x * 256 + threadIdx.x;     // 0..32767
    const int c    = s >> 10;
    const int r    = s & 1023;
    const int l    = r & 63;
    const int nt   = (r >> 6) & 1;
    const int kh   = (r >> 7) & 1;
    const int term = (r >> 8) & 1;
    const int eh   = (r >> 9) & 1;
    const int e = eh * 32 + nt * 16 + (l & 15);
    const int k = c * 64 + kh * 32 + (l >> 4) * 8;

    const float* src = w + (size_t)e * HIDDEN + k;
    union { _Float16 f[8]; uint4 u; } o;
    #pragma unroll
    for (int j = 0; j < 8; ++j) {
        const float v = src[j];
        const _Float16 h = (_Float16)v;
        o.f[j] = (term == 0) ? h : (_Float16)((v - (float)h) * 4096.f);
    }
    wimg[s] = o.u;
}

// fp32 -> (hi, lo*4096) fp16x8 split of 8 floats [verified R3]
__device__ __forceinline__ void cvt_split(const float4 a, const float4 b,
                                          f16x8& hi, f16x8& lo) {
    union { _Float16 f[8]; f16x8 v; } H, L;
    #pragma unroll
    for (int j = 0; j < 4; ++j) {
        const float s0 = (&a.x)[j];
        const float s1 = (&b.x)[j];
        const _Float16 h0 = (_Float16)s0;
        const _Float16 h1 = (_Float16)s1;
        H.f[j]     = h0;
        H.f[j + 4] = h1;
        L.f[j]     = (_Float16)((s0 - (float)h0) * 4096.f);
        L.f[j + 4] = (_Float16)((s1 - (float)h1) * 4096.f);
    }
    hi = H.v; lo = L.v;
}

// ---------------------------------------------------------------------------
// R7: DMA-pipelined router. R6 post-mortem: compiler sinks register-destined
// loads to uses (VGPR 44/56 across 3 structures), collapsing every register
// pipeline -> 78us latency-bound. global_load_lds has NO dest register, so
// the pipeline is structural. 1024 blocks x 4 waves, MT=16; k chunked BK=256,
// 8 chunks, ONE barrier per chunk (m97 pattern: DMA c+1 issued at body top,
// in flight across compute, drained at end barrier). Waves split each chunk's
// k 4-ways (64 k/wave = 2 MFMA steps). x staged with row-contiguous 1-KB DMA
// per call + XOR swizzle (kb^=(row&7)<<4) applied to the GLOBAL source and
// the LDS read (both-sides): breaks the 16-way row-stride bank conflict.
// B(c) reg loads issued BEFORE DMA(c+1) -> auto-wait is vmcnt(4), DMA stays
// in flight. LDS: xbuf 32KB overlaid with epilogue logits lg (loop's final
// barrier separates). Routing math + wimg layout unchanged [verified].
// ---------------------------------------------------------------------------
__global__ __launch_bounds__(256, 3) void router_main(
    const float* __restrict__ x, const uint4* __restrict__ wimg,
    float* __restrict__ out, float* __restrict__ zpartial)
{
    __shared__ __align__(16) unsigned char smem[2 * MT * ROWB];  // 32768 B
    __shared__ float zred[4];
    float* lg = (float*)smem;            // epilogue overlay: [4][MT*66] fp32

    const int tid  = threadIdx.x;
    const int wv   = __builtin_amdgcn_readfirstlane(tid >> 6);
    const int lane = tid & 63;
    const int t0   = blockIdx.x * MT;

    const int row_r = lane & 15;                 // A-frag row (token)
    const int kgrp  = lane >> 4;                 // 0..3
    const int sr    = (row_r & 7) << 4;          // read-side swizzle

    // ---- DMA source setup: wave wv stages rows wv*4+p (p=0..3), 1 KB each.
    // Lane l writes LDS [row*1024 + l*16] from global x_row[c*1024 + (l*16 ^ srow)]
    const float* xg[4];
    #pragma unroll
    for (int p = 0; p < 4; ++p) {
        const int row  = wv * 4 + p;
        const int srow = (row & 7) << 4;
        xg[p] = x + (size_t)(t0 + row) * HIDDEN + (((lane * 16) ^ srow) >> 2);
    }

    f32x4 acc0[4], acc1[4];
    #pragma unroll
    for (int g = 0; g < 4; ++g) { acc0[g] = (f32x4)0.f; acc1[g] = (f32x4)0.f; }

    // prologue: DMA chunk 0 into buf 0, then barrier (drains DMA, publishes)
    #pragma unroll
    for (int p = 0; p < 4; ++p)
        dma16(xg[p], smem + (wv * 4 + p) * ROWB);
    __syncthreads();

    #pragma unroll
    for (int c = 0; c < NCH; ++c) {
        const int buf = c & 1;

        // ---- B(c): both k-steps upfront (16 loads) BEFORE the DMA issue,
        // so the compiler's B-wait is vmcnt(4) and DMA(c+1) stays in flight.
        const uint4* p0 = wimg + (size_t)(c * 4 + wv) * 1024 + lane;
        f16x8 bh[2][4], bl[2][4];
        #pragma unroll
        for (int st = 0; st < 2; ++st) {
            const uint4* p = p0 + st * 128;
            bh[st][0] = *(const f16x8*)(p);          // eh0 nt0 hi
            bh[st][1] = *(const f16x8*)(p + 64);     // eh0 nt1 hi
            bh[st][2] = *(const f16x8*)(p + 512);    // eh1 nt0 hi
            bh[st][3] = *(const f16x8*)(p + 576);    // eh1 nt1 hi
            bl[st][0] = *(const f16x8*)(p + 256);
            bl[st][1] = *(const f16x8*)(p + 320);
            bl[st][2] = *(const f16x8*)(p + 768);
            bl[st][3] = *(const f16x8*)(p + 832);
        }

        // ---- issue DMA for chunk c+1 into the other buffer
        if (c + 1 < NCH) {
            #pragma unroll
            for (int p = 0; p < 4; ++p)
                dma16(xg[p] + (c + 1) * BK,
                      smem + (buf ^ 1) * (MT * ROWB) + (wv * 4 + p) * ROWB);
        }

        // ---- compute 2 k-steps from buf (DMA'd last iter, barrier-published)
        const unsigned char* abase = smem + buf * (MT * ROWB) + row_r * ROWB;
        #pragma unroll
        for (int st = 0; st < 2; ++st) {
            const int kb0 = wv * 256 + st * 128 + kgrp * 32;
            const float4 va = *(const float4*)(abase + (kb0 ^ sr));
            const float4 vb = *(const float4*)(abase + ((kb0 + 16) ^ sr));
            f16x8 Ah, Al;
            cvt_split(va, vb, Ah, Al);
            #pragma unroll
            for (int g = 0; g < 4; ++g) {
                acc0[g] = __builtin_amdgcn_mfma_f32_16x16x32_f16(Ah, bh[st][g], acc0[g], 0, 0, 0);
                acc1[g] = __builtin_amdgcn_mfma_f32_16x16x32_f16(Ah, bl[st][g], acc1[g], 0, 0, 0);
                acc1[g] = __builtin_amdgcn_mfma_f32_16x16x32_f16(Al, bh[st][g], acc1[g], 0, 0, 0);
            }
        }

        // publishes buf^1 (DMA drained here) + guards xbuf WAR for next iter
        __syncthreads();
    }

    // ---- epilogue: k-partial logits into lg (xbuf dead; barrier above) ----
    #pragma unroll
    for (int g = 0; g < 4; ++g)
        #pragma unroll
        for (int r = 0; r < 4; ++r) {
            const int tok = kgrp * 4 + r;                               // C/D row
            const int e   = (g >> 1) * 32 + (g & 1) * 16 + row_r;       // C/D col
            lg[wv * (MT * 66) + tok * 66 + e] = acc0[g][r] + acc1[g][r] * (1.f / 4096.f);
        }
    __syncthreads();

    // ---- routing (R1-verified math): wave handles 4 tokens, lane = expert ----
    float zsum = 0.f;
    for (int tt = 0; tt < 4; ++tt) {
        const int t = wv * 4 + tt;
        const int li = t * 66 + lane;
        const float v = lg[0 * (MT * 66) + li] + lg[1 * (MT * 66) + li]
                      + lg[2 * (MT * 66) + li] + lg[3 * (MT * 66) + li];

        float bv = v; int bi = lane;
        #pragma unroll
        for (int s = 1; s < 64; s <<= 1) {
            const float ov = __shfl_xor(bv, s, 64);
            const int   oi = __shfl_xor(bi, s, 64);
            if (ov > bv || (ov == bv && oi < bi)) { bv = ov; bi = oi; }
        }
        const float max1 = bv; const int s1 = bi;

        const float e1 = expf(v - max1);
        const float sume = wave_sum64(e1);
        out[GATES_OFF + (size_t)(t0 + t) * NEXP + lane] = e1 / sume;
        const float lse = max1 + logf(sume);
        zsum += lse * lse;

        const bool mask1 = (max1 - v) > 0.02f * fmaxf(fabsf(v), max1);
        const float sum1 = wave_sum64(mask1 ? 0.f : e1);

        float bv2 = (lane == s1) ? -INFINITY : v; int bi2 = lane;
        #pragma unroll
        for (int s = 1; s < 64; s <<= 1) {
            const float ov = __shfl_xor(bv2, s, 64);
            const int   oi = __shfl_xor(bi2, s, 64);
            if (ov > bv2 || (ov == bv2 && oi < bi2)) { bv2 = ov; bi2 = oi; }
        }
        const float max2 = bv2; const int s2 = bi2;

        const bool mask2 = (max2 - v) > 0.02f * fmaxf(fabsf(v), max2);
        const float p2v = (mask2 || lane == s1) ? 0.f : expf(v - max2);
        const float sum2 = wave_sum64(p2v);

        if (lane == 0) {
            const size_t trow = (size_t)(t0 + t) * 2;
            out[trow + 0] = 1.f / sum1;
            out[trow + 1] = 1.f / sum2;
            out[SEL_OFF + trow + 0] = (float)s1;
            out[SEL_OFF + trow + 1] = (float)s2;
        }
    }

    if (lane == 0) zred[wv] = zsum;
    __syncthreads();
    if (tid == 0)
        zpartial[blockIdx.x] = zred[0] + zred[1] + zred[2] + zred[3];
}

__global__ __launch_bounds__(256) void zfinal(
    const float* __restrict__ zpartial, float* __restrict__ out)
{
    const int tid = threadIdx.x;                 // 1024 partials, 256 threads
    float v = zpartial[tid] + zpartial[tid + 256]
            + zpartial[tid + 512] + zpartial[tid + 768];
    v = wave_sum64(v);
    __shared__ float red[4];
    if ((tid & 63) == 0) red[tid >> 6] = v;
    __syncthreads();
    if (tid == 0) {
        const float tot = red[0] + red[1] + red[2] + red[3];
        out[Z_OFF] = 0.001f * (tot / (float)TOKENS);
    }
}

extern "C" void kernel_launch(void* const* d_in, const int* in_sizes, int n_in,
                              void* d_out, int out_size, void* d_ws, size_t ws_size,
                              hipStream_t stream) {
    const float* x = (const float*)d_in[0];   // [16384, 2048] fp32
    const float* w = (const float*)d_in[1];   // [64, 2048] fp32
    float* out = (float*)d_out;               // mult(32768) | gates(1048576) | sel(32768) | z(1)

    uint4* wimg     = (uint4*)d_ws;                               // 512 KB
    float* zpartial = (float*)((char*)d_ws + WIMG_BYTES);         // 1024 floats

    wconvert<<<128, 256, 0, stream>>>(w, wimg);
    router_main<<<NBLK, 256, 0, stream>>>(x, wimg, out, zpartial);
    zfinal<<<1, 256, 0, stream>>>(zpartial, out);
}